// Round 4
// baseline (187.941 us; speedup 1.0000x reference)
//
#include <hip/hip_runtime.h>

typedef unsigned short u16;
typedef __bf16 bf16x8 __attribute__((ext_vector_type(8)));
typedef float f32x4 __attribute__((ext_vector_type(4)));
typedef unsigned short u16x8 __attribute__((ext_vector_type(8)));
typedef unsigned short u16x4 __attribute__((ext_vector_type(4)));

#define NB 8
#define NC 640
#define NN 4096
#define NL 77
#define NCD 768
#define NH 8
#define NDH 80
#define NT 10  // K-tiles of 64 in the 640-deep GEMMs

__device__ __forceinline__ u16 f2bf(float f) {
  unsigned u = __builtin_bit_cast(unsigned, f);
  u += 0x7fffu + ((u >> 16) & 1u);   // RNE
  return (u16)(u >> 16);
}

__device__ __forceinline__ f32x4 mfma16(bf16x8 a, bf16x8 b, f32x4 c) {
  return __builtin_amdgcn_mfma_f32_16x16x32_bf16(a, b, c, 0, 0, 0);
}

__device__ __forceinline__ void gload_lds16(const void* g, void* l) {
  __builtin_amdgcn_global_load_lds(
      (const __attribute__((address_space(1))) void*)g,
      (__attribute__((address_space(3))) void*)l, 16, 0, 0);
}

// ---------------- P1: hs (B,C,N) f32 -> xbf (B,N,C) bf16 (transpose+convert)
__global__ __launch_bounds__(256) void k_prep_x(const float* __restrict__ hs,
                                                u16* __restrict__ xbf) {
  __shared__ float tls[64][69];  // 69: read stride 276B == 20 mod 32 banks -> 2-way (free)
  const int n0 = blockIdx.x * 64;   // 64
  const int c0 = blockIdx.y * 64;   // 10
  const int b  = blockIdx.z;        // 8
  const int t = threadIdx.x;
  const int rr = t >> 4;            // 0..15
  const int cc = (t & 15) * 4;      // 0..60
#pragma unroll
  for (int p = 0; p < 4; ++p) {
    int c = p * 16 + rr;
    float4 v = *(const float4*)(hs + ((size_t)(b * NC + c0 + c) << 12) + n0 + cc);
    *(float4*)&tls[c][cc] = v;
  }
  __syncthreads();
#pragma unroll
  for (int p = 0; p < 4; ++p) {
    int n = p * 16 + rr;
    u16x4 o;
#pragma unroll
    for (int e = 0; e < 4; ++e) o[e] = f2bf(tls[cc + e][n]);
    *(u16x4*)(xbf + ((size_t)(b * NN + n0 + n)) * NC + c0 + cc) = o;
  }
}

// ---------------- P2: Wq,Wo (k,n) f32 -> (n,k) bf16 ; scale folded into Wq
__global__ __launch_bounds__(256) void k_prep_w(const float* __restrict__ Wq,
                                                const float* __restrict__ Wo,
                                                u16* __restrict__ wqt,
                                                u16* __restrict__ wot) {
  __shared__ float tls[32][33];
  const int which = blockIdx.z;
  const float* in = which ? Wo : Wq;
  u16* outp = which ? wot : wqt;
  const float scale = which ? 1.0f : 0.11180339887498949f;  // 1/sqrt(80)
  const int n0 = blockIdx.x * 32, k0 = blockIdx.y * 32;
  const int t = threadIdx.x;
  const int r = t >> 3, c4 = (t & 7) * 4;
  float4 v = *(const float4*)(in + (size_t)(k0 + r) * NC + n0 + c4);
  tls[r][c4 + 0] = v.x; tls[r][c4 + 1] = v.y; tls[r][c4 + 2] = v.z; tls[r][c4 + 3] = v.w;
  __syncthreads();
  u16x4 o;
#pragma unroll
  for (int e = 0; e < 4; ++e) o[e] = f2bf(tls[c4 + e][r] * scale);
  *(u16x4*)(outp + (size_t)(n0 + r) * NC + k0 + c4) = o;
}

// ---------------- P3: K,V = ehs @ Wk/Wv
// kbf: (B,H, 80(l,pad), 80(d)) bf16 row-major (pad rows untouched, masked downstream)
// vtbf: (B,H, 80(d), 96(l,pad)) bf16 — V transposed; pad l-cols (77..95) zeroed here
__global__ __launch_bounds__(256) void k_kv(const float* __restrict__ ehs,
                                            const float* __restrict__ Wk,
                                            const float* __restrict__ Wv,
                                            u16* __restrict__ kbf,
                                            u16* __restrict__ vtbf) {
  const int l = blockIdx.x;            // 0..95
  const int cg = blockIdx.y;           // 10
  const int t = threadIdx.x;
  if (l >= NL) {                       // zero the vtbf pad columns
    if (t < 64) {
      int c = cg * 64 + t;
      int h = c / NDH, d = c % NDH;
#pragma unroll
      for (int b = 0; b < NB; ++b)
        vtbf[(((size_t)(b * NH + h)) * NDH + d) * 96 + l] = 0;
    }
    return;
  }
  __shared__ float es[NB][NCD];        // 24 KB
  __shared__ float comb[3][64][17];    // 13 KB
#pragma unroll
  for (int j = 0; j < 6; ++j) {
    int idx = (t + j * 256) * 4;
    int b = idx / NCD, k = idx % NCD;
    *(float4*)&es[b][k] = *(const float4*)(ehs + ((size_t)(b * NL + l)) * NCD + k);
  }
  __syncthreads();
  const int col = t & 63, kq = t >> 6;
  const int c = cg * 64 + col;
  float ak[NB], av[NB];
#pragma unroll
  for (int b = 0; b < NB; ++b) { ak[b] = 0.f; av[b] = 0.f; }
  const int kbeg = kq * 192, kend = kbeg + 192;
#pragma unroll 4
  for (int k = kbeg; k < kend; ++k) {
    float wk = Wk[(size_t)k * NC + c];
    float wv = Wv[(size_t)k * NC + c];
#pragma unroll
    for (int b = 0; b < NB; ++b) {
      ak[b] = fmaf(es[b][k], wk, ak[b]);
      av[b] = fmaf(es[b][k], wv, av[b]);
    }
  }
  if (kq) {
#pragma unroll
    for (int b = 0; b < NB; ++b) {
      comb[kq - 1][col][b] = ak[b];
      comb[kq - 1][col][8 + b] = av[b];
    }
  }
  __syncthreads();
  if (kq == 0) {
#pragma unroll
    for (int b = 0; b < NB; ++b) {
#pragma unroll
      for (int q = 0; q < 3; ++q) {
        ak[b] += comb[q][col][b];
        av[b] += comb[q][col][8 + b];
      }
    }
    const int h = c / NDH, d = c % NDH;
#pragma unroll
    for (int b = 0; b < NB; ++b) {
      kbf[(((size_t)(b * NH + h)) * 80 + l) * 80 + d] = f2bf(ak[b]);
      vtbf[(((size_t)(b * NH + h)) * NDH + d) * 96 + l] = f2bf(av[b]);
    }
  }
}

// ---------------- G: C(32768x640) = A(32768x640,bf16) @ Bw^T(640x640 [n][k],bf16)
// Counted-vmcnt ring-3 pipeline (T3/T4 minimum form):
//   BM=256 x BN=128, BK=64, 512 threads = 8 waves (4M x 2N, 64x64/wave).
//   3 LDS tile-buffers (144 KB): 2 tiles always prefetched ahead; per K-tile
//   wait vmcnt(12) (never 0 in steady state), raw s_barrier (NOT __syncthreads
//   which drains vmcnt(0)), 16 ds_read_b128 + 32 MFMA, barrier, then re-stage
//   the freed buffer. Per-wave FIFO: 6 gload_lds per tile, oldest-first.
// MODE 0: out bf16 (B,N,C)  (operand-swapped MFMA so D row<->c, col<->n)
// MODE 1: out f32  (B,C,N) + bias
template <int MODE>
__global__ __launch_bounds__(512) void k_gemm(const u16* __restrict__ A,
                                              const u16* __restrict__ Bw,
                                              const float* __restrict__ bias,
                                              u16* __restrict__ outb,
                                              float* __restrict__ outf) {
  __shared__ __align__(16) u16 lds[3][24576];  // per buf: A[0..16384) B[16384..24576)
  const int bid = blockIdx.x;
  const int logical = (bid & 7) * 80 + (bid >> 3);  // T1 XCD swizzle (640%8==0)
  const int cb = logical % 5, rb = logical / 5;
  const int r0 = rb * 256, c0 = cb * 128;
  const int t = threadIdx.x;
  const int w = t >> 6, lane = t & 63;
  const int wm = w >> 1, wn = w & 1;
  const int fr = lane & 15, g = lane >> 4;
  const int lr = lane >> 3, ls = lane & 7;
  const int sslot = ls ^ lr;  // pre-swizzled k-slot (T2; LDS stays linear for gload_lds)

  f32x4 acc[4][4];
  f32x4 z4 = {0.f, 0.f, 0.f, 0.f};
#pragma unroll
  for (int i = 0; i < 4; ++i)
#pragma unroll
    for (int j = 0; j < 4; ++j) acc[i][j] = z4;

  // stage tile kt into buf: A 32 chunks (8 rows ea), B 16 chunks; 6 loads/wave
#define STAGE(kt, buf)                                                              \
  {                                                                                 \
    const int k0_ = (kt)*64;                                                        \
    u16* base_ = &lds[(buf)][0];                                                    \
    _Pragma("unroll") for (int p = 0; p < 4; ++p) {                                 \
      int ch = w * 4 + p;                                                           \
      int row = ch * 8 + lr;                                                        \
      gload_lds16(A + (size_t)(r0 + row) * NC + k0_ + sslot * 8, base_ + ch * 512); \
    }                                                                               \
    _Pragma("unroll") for (int p = 0; p < 2; ++p) {                                 \
      int ch = w * 2 + p;                                                           \
      int row = ch * 8 + lr;                                                        \
      gload_lds16(Bw + (size_t)(c0 + row) * NC + k0_ + sslot * 8,                   \
                  base_ + 16384 + ch * 512);                                        \
    }                                                                               \
  }

  STAGE(0, 0);
  STAGE(1, 1);
  STAGE(2, 2);

#pragma unroll
  for (int kt = 0; kt < NT; ++kt) {
    const int buf = kt % 3;
    if (kt <= NT - 3)
      asm volatile("s_waitcnt vmcnt(12)" ::: "memory");
    else if (kt == NT - 2)
      asm volatile("s_waitcnt vmcnt(6)" ::: "memory");
    else
      asm volatile("s_waitcnt vmcnt(0)" ::: "memory");
    __builtin_amdgcn_s_barrier();

    const char* bA = (const char*)&lds[buf][0];
    const char* bB = (const char*)&lds[buf][16384];
    bf16x8 af[4][2], bfr[4][2];
#pragma unroll
    for (int kk = 0; kk < 2; ++kk) {
#pragma unroll
      for (int mt = 0; mt < 4; ++mt) {
        int row = wm * 64 + mt * 16 + fr;
        af[mt][kk] = *(const bf16x8*)(bA + row * 128 +
                                      ((kk * 64 + g * 16) ^ ((row & 7) << 4)));
      }
#pragma unroll
      for (int nt = 0; nt < 4; ++nt) {
        int row = wn * 64 + nt * 16 + fr;
        bfr[nt][kk] = *(const bf16x8*)(bB + row * 128 +
                                       ((kk * 64 + g * 16) ^ ((row & 7) << 4)));
      }
    }
    __builtin_amdgcn_s_setprio(1);
#pragma unroll
    for (int kk = 0; kk < 2; ++kk)
#pragma unroll
      for (int mt = 0; mt < 4; ++mt)
#pragma unroll
        for (int nt = 0; nt < 4; ++nt) {
          if (MODE == 0)
            acc[mt][nt] = mfma16(bfr[nt][kk], af[mt][kk], acc[mt][nt]);
          else
            acc[mt][nt] = mfma16(af[mt][kk], bfr[nt][kk], acc[mt][nt]);
        }
    __builtin_amdgcn_s_setprio(0);
    __builtin_amdgcn_s_barrier();  // all waves done reading buf
    if (kt + 3 < NT) STAGE(kt + 3, buf);
  }
#undef STAGE

  const int b = r0 >> 12, n0 = r0 & 4095;
  if (MODE == 0) {
    // D[row=g*4+r <-> c][col=fr <-> n]; write (B,N,C), contiguous along c
#pragma unroll
    for (int mt = 0; mt < 4; ++mt) {
      int n = n0 + wm * 64 + mt * 16 + fr;
#pragma unroll
      for (int nt = 0; nt < 4; ++nt) {
        int cbs = c0 + wn * 64 + nt * 16 + g * 4;
        u16x4 o;
#pragma unroll
        for (int r2 = 0; r2 < 4; ++r2) o[r2] = f2bf(acc[mt][nt][r2]);
        *(u16x4*)(outb + ((size_t)(b * NN + n)) * NC + cbs) = o;
      }
    }
  } else {
    // D[row=g*4+r <-> n][col=fr <-> c]; write (B,C,N) f32 + bias
#pragma unroll
    for (int mt = 0; mt < 4; ++mt) {
      int n = n0 + wm * 64 + mt * 16 + g * 4;
#pragma unroll
      for (int nt = 0; nt < 4; ++nt) {
        int c = c0 + wn * 64 + nt * 16 + fr;
        float bv = bias[c];
        f32x4 o;
#pragma unroll
        for (int r2 = 0; r2 < 4; ++r2) o[r2] = acc[mt][nt][r2] + bv;
        *(f32x4*)(outf + (((size_t)(b * NC + c)) << 12) + n) = o;
      }
    }
  }
}

// ---------------- A1: fused attention, one (b,h,64 q-rows) per block
// qbf (B,N,C) bf16 (scale folded); kbf (B,H,80,80); vtbf (B,H,80,96); obf (B,N,C)
// Swapped QK^T: S[l][n] so softmax reduce = per-lane + 2 shfl_xor.
// Only LDS use: per-wave 16x104 P bounce (vectorized, conflict-free).
__global__ __launch_bounds__(256) void k_attn(const u16* __restrict__ qbf,
                                              const u16* __restrict__ kbf,
                                              const u16* __restrict__ vtbf,
                                              u16* __restrict__ obf) {
  __shared__ __align__(16) u16 sP[4][16][104];
  const int bid = blockIdx.x;
  const int n0 = (bid & 63) * 64, h = (bid >> 6) & 7, b = bid >> 9;
  const int t = threadIdx.x, w = t >> 6, lane = t & 63;
  const int fr = lane & 15, g = lane >> 4;

  // Q fragments: arg2 role, fr = q-row, 8 d-elems per (kk,g)
  const size_t qrow = ((size_t)(b * NN + n0 + w * 16 + fr)) * NC + h * NDH;
  bf16x8 qf[3];
#pragma unroll
  for (int kk = 0; kk < 3; ++kk) {
    int d0 = kk * 32 + g * 8;
    bf16x8 v = {};
    if (d0 < NDH) v = *(const bf16x8*)(qbf + qrow + d0);
    qf[kk] = v;
  }
  // QK^T swapped: S tile nt: row(g*4+r)=l-16nt, col(fr)=n-local
  const size_t kbase = ((size_t)(b * NH + h)) * (80 * 80);
  f32x4 s[5];
  f32x4 z4 = {0.f, 0.f, 0.f, 0.f};
#pragma unroll
  for (int nt = 0; nt < 5; ++nt) s[nt] = z4;
#pragma unroll
  for (int nt = 0; nt < 5; ++nt) {
    const u16* krow = kbf + kbase + (size_t)(nt * 16 + fr) * 80;
#pragma unroll
    for (int kk = 0; kk < 3; ++kk) {
      int d0 = kk * 32 + g * 8;
      bf16x8 kv = {};
      if (d0 < NDH) kv = *(const bf16x8*)(krow + d0);
      s[nt] = mfma16(kv, qf[kk], s[nt]);
    }
  }
  // V^T fragments issued early (independent of softmax)
  const size_t vbase = ((size_t)(b * NH + h)) * (80 * 96);
  bf16x8 vf[5][3];
#pragma unroll
  for (int nt = 0; nt < 5; ++nt)
#pragma unroll
    for (int kk = 0; kk < 3; ++kk)
      vf[nt][kk] = *(const bf16x8*)(vtbf + vbase + (size_t)(nt * 16 + fr) * 96 +
                                    kk * 32 + g * 8);
  // softmax over l (per-lane 20 vals + 2 shfls); no max-sub (|s| small, f32-safe)
  float sum = 0.f;
#pragma unroll
  for (int nt = 0; nt < 5; ++nt)
#pragma unroll
    for (int r = 0; r < 4; ++r) {
      int l = nt * 16 + g * 4 + r;
      float ev = (l < NL) ? __expf(s[nt][r]) : 0.f;
      s[nt][r] = ev;
      sum += ev;
    }
  sum += __shfl_xor(sum, 16);
  sum += __shfl_xor(sum, 32);
  float inv = 1.0f / sum;
  // P -> per-wave LDS tile [n_local=fr][l], normalized bf16
#pragma unroll
  for (int nt = 0; nt < 5; ++nt) {
    u16x4 o;
#pragma unroll
    for (int r = 0; r < 4; ++r) o[r] = f2bf(s[nt][r] * inv);
    *(u16x4*)&sP[w][fr][nt * 16 + g * 4] = o;
  }
  __syncthreads();
  // PV: O[n][d] = P[n][l] V^T[d][l]
  bf16x8 ap[3];
#pragma unroll
  for (int kk = 0; kk < 3; ++kk) {
    int l0 = kk * 32 + g * 8;
    bf16x8 v = {};
    if (l0 < 80) v = *(const bf16x8*)&sP[w][fr][l0];
    ap[kk] = v;
  }
  f32x4 o[5];
#pragma unroll
  for (int nt = 0; nt < 5; ++nt) o[nt] = z4;
#pragma unroll
  for (int nt = 0; nt < 5; ++nt)
#pragma unroll
    for (int kk = 0; kk < 3; ++kk)
      o[nt] = mfma16(ap[kk], vf[nt][kk], o[nt]);
  // store: O[n = n0+w*16+g*4+r][d = nt*16+fr] -> obf (B,N,C)
#pragma unroll
  for (int nt = 0; nt < 5; ++nt)
#pragma unroll
    for (int r = 0; r < 4; ++r)
      obf[((size_t)(b * NN + n0 + w * 16 + g * 4 + r)) * NC + h * NDH + nt * 16 + fr] =
          f2bf(o[nt][r]);
}

// ---------------- saliency: softmax row-mean is exactly 1/L
__global__ void k_sal(float* __restrict__ sal) {
  int i = blockIdx.x * 256 + threadIdx.x;
  if (i < NB * NN) sal[i] = 1.0f / 77.0f;
}

extern "C" void kernel_launch(void* const* d_in, const int* in_sizes, int n_in,
                              void* d_out, int out_size, void* d_ws, size_t ws_size,
                              hipStream_t stream) {
  const float* hs  = (const float*)d_in[0];
  const float* ehs = (const float*)d_in[1];
  const float* Wq  = (const float*)d_in[2];
  const float* Wk  = (const float*)d_in[3];
  const float* Wv  = (const float*)d_in[4];
  const float* Wo  = (const float*)d_in[5];
  const float* bo  = (const float*)d_in[6];
  float* out = (float*)d_out;
  float* sal = out + (size_t)NB * NC * NN;

  u16* ws16 = (u16*)d_ws;
  const size_t xn = (size_t)NB * NN * NC;  // 20,971,520
  u16* xbf = ws16;            // also obf (xbf dead after gemm<0>)
  u16* qbf = ws16 + xn;
  u16* wqt = qbf + xn;
  u16* wot = wqt + (size_t)NC * NC;
  u16* kbf = wot + (size_t)NC * NC;                 // B*H*80*80
  u16* vtbf = kbf + (size_t)NB * NH * 80 * 80;      // B*H*80*96
  u16* obf = xbf;

  k_prep_w<<<dim3(20, 20, 2), 256, 0, stream>>>(Wq, Wo, wqt, wot);
  k_kv<<<dim3(96, 10), 256, 0, stream>>>(ehs, Wk, Wv, kbf, vtbf);
  k_prep_x<<<dim3(64, 10, NB), 256, 0, stream>>>(hs, xbf);
  k_gemm<0><<<640, 512, 0, stream>>>(xbf, wqt, nullptr, qbf, nullptr);
  k_attn<<<NB * NH * 64, 256, 0, stream>>>(qbf, kbf, vtbf, obf);
  k_gemm<1><<<640, 512, 0, stream>>>(obf, wot, bo, nullptr, out);
  k_sal<<<128, 256, 0, stream>>>(sal);
}

// Round 5
// 163.255 us; speedup vs baseline: 1.1512x; 1.1512x over previous
//
#include <hip/hip_runtime.h>

typedef unsigned short u16;
typedef __bf16 bf16x8 __attribute__((ext_vector_type(8)));
typedef float f32x4 __attribute__((ext_vector_type(4)));
typedef unsigned short u16x8 __attribute__((ext_vector_type(8)));
typedef unsigned short u16x4 __attribute__((ext_vector_type(4)));

#define NB 8
#define NC 640
#define NN 4096
#define NL 77
#define NCD 768
#define NH 8
#define NDH 80

__device__ __forceinline__ u16 f2bf(float f) {
  unsigned u = __builtin_bit_cast(unsigned, f);
  u += 0x7fffu + ((u >> 16) & 1u);   // RNE
  return (u16)(u >> 16);
}

__device__ __forceinline__ f32x4 mfma16(bf16x8 a, bf16x8 b, f32x4 c) {
  return __builtin_amdgcn_mfma_f32_16x16x32_bf16(a, b, c, 0, 0, 0);
}

__device__ __forceinline__ void gload_lds16(const void* g, void* l) {
  __builtin_amdgcn_global_load_lds(
      (const __attribute__((address_space(1))) void*)g,
      (__attribute__((address_space(3))) void*)l, 16, 0, 0);
}

// ---------------- merged prep: [0,800) prep_w | [800,1760) kv | [1760,6880) prep_x | [6880,7008) sal
// All four are mutually independent; one dispatch removes 3 launch gaps and
// overlaps kv under prep_x. LDS = union (kv's 37.6 KB is max).
__global__ __launch_bounds__(256) void k_prep(const float* __restrict__ hs,
                                              const float* __restrict__ ehs,
                                              const float* __restrict__ Wq,
                                              const float* __restrict__ Wk,
                                              const float* __restrict__ Wv,
                                              const float* __restrict__ Wo,
                                              u16* __restrict__ xbf,
                                              u16* __restrict__ wqt,
                                              u16* __restrict__ wot,
                                              u16* __restrict__ kbf,
                                              u16* __restrict__ vtbf,
                                              float* __restrict__ sal) {
  __shared__ __align__(16) char smem[37888];
  const int bid = blockIdx.x;
  const int t = threadIdx.x;

  if (bid < 800) {
    // ---- prep_w: Wq,Wo (k,n) f32 -> (n,k) bf16; scale folded into Wq
    float(*tls)[33] = (float(*)[33])smem;
    const int which = bid / 400;
    const int rem = bid % 400;
    const float* in = which ? Wo : Wq;
    u16* outp = which ? wot : wqt;
    const float scale = which ? 1.0f : 0.11180339887498949f;  // 1/sqrt(80)
    const int n0 = (rem % 20) * 32, k0 = (rem / 20) * 32;
    const int r = t >> 3, c4 = (t & 7) * 4;
    float4 v = *(const float4*)(in + (size_t)(k0 + r) * NC + n0 + c4);
    tls[r][c4 + 0] = v.x; tls[r][c4 + 1] = v.y; tls[r][c4 + 2] = v.z; tls[r][c4 + 3] = v.w;
    __syncthreads();
    u16x4 o;
#pragma unroll
    for (int e = 0; e < 4; ++e) o[e] = f2bf(tls[c4 + e][r] * scale);
    *(u16x4*)(outp + (size_t)(n0 + r) * NC + k0 + c4) = o;
    return;
  }
  if (bid < 1760) {
    // ---- kv: K,V = ehs @ Wk/Wv
    // kbf (B,H,80l,80d) pad rows untouched (masked downstream);
    // vtbf (B,H,80d,96l) pad l-cols zeroed
    const int i = bid - 800;
    const int l = i % 96, cg = i / 96;
    if (l >= NL) {
      if (t < 64) {
        int c = cg * 64 + t;
        int h = c / NDH, d = c % NDH;
#pragma unroll
        for (int b = 0; b < NB; ++b)
          vtbf[(((size_t)(b * NH + h)) * NDH + d) * 96 + l] = 0;
      }
      return;
    }
    float(*es)[NCD] = (float(*)[NCD])smem;                       // 24 KB
    float(*comb)[64][17] = (float(*)[64][17])(smem + 24576);     // 13 KB
#pragma unroll
    for (int j = 0; j < 6; ++j) {
      int idx = (t + j * 256) * 4;
      int b = idx / NCD, k = idx % NCD;
      *(float4*)&es[b][k] = *(const float4*)(ehs + ((size_t)(b * NL + l)) * NCD + k);
    }
    __syncthreads();
    const int col = t & 63, kq = t >> 6;
    const int c = cg * 64 + col;
    float ak[NB], av[NB];
#pragma unroll
    for (int b = 0; b < NB; ++b) { ak[b] = 0.f; av[b] = 0.f; }
    const int kbeg = kq * 192, kend = kbeg + 192;
#pragma unroll 4
    for (int k = kbeg; k < kend; ++k) {
      float wk = Wk[(size_t)k * NC + c];
      float wv = Wv[(size_t)k * NC + c];
#pragma unroll
      for (int b = 0; b < NB; ++b) {
        ak[b] = fmaf(es[b][k], wk, ak[b]);
        av[b] = fmaf(es[b][k], wv, av[b]);
      }
    }
    if (kq) {
#pragma unroll
      for (int b = 0; b < NB; ++b) {
        comb[kq - 1][col][b] = ak[b];
        comb[kq - 1][col][8 + b] = av[b];
      }
    }
    __syncthreads();
    if (kq == 0) {
#pragma unroll
      for (int b = 0; b < NB; ++b) {
#pragma unroll
        for (int q = 0; q < 3; ++q) {
          ak[b] += comb[q][col][b];
          av[b] += comb[q][col][8 + b];
        }
      }
      const int h = c / NDH, d = c % NDH;
#pragma unroll
      for (int b = 0; b < NB; ++b) {
        kbf[(((size_t)(b * NH + h)) * 80 + l) * 80 + d] = f2bf(ak[b]);
        vtbf[(((size_t)(b * NH + h)) * NDH + d) * 96 + l] = f2bf(av[b]);
      }
    }
    return;
  }
  if (bid < 6880) {
    // ---- prep_x: hs (B,C,N) f32 -> xbf (B,N,C) bf16 (transpose+convert)
    float(*tls)[69] = (float(*)[69])smem;  // stride 69: 2-way bank alias (free)
    const int i = bid - 1760;
    const int n0 = (i % 64) * 64;
    const int c0 = ((i / 64) % 10) * 64;
    const int b = i / 640;
    const int rr = t >> 4;
    const int cc = (t & 15) * 4;
#pragma unroll
    for (int p = 0; p < 4; ++p) {
      int c = p * 16 + rr;
      float4 v = *(const float4*)(hs + ((size_t)(b * NC + c0 + c) << 12) + n0 + cc);
      *(float4*)&tls[c][cc] = v;
    }
    __syncthreads();
#pragma unroll
    for (int p = 0; p < 4; ++p) {
      int n = p * 16 + rr;
      u16x4 o;
#pragma unroll
      for (int e = 0; e < 4; ++e) o[e] = f2bf(tls[cc + e][n]);
      *(u16x4*)(xbf + ((size_t)(b * NN + n0 + n)) * NC + c0 + cc) = o;
    }
    return;
  }
  {
    // ---- saliency: softmax row-mean is exactly 1/L
    int i = (bid - 6880) * 256 + t;
    if (i < NB * NN) sal[i] = 1.0f / 77.0f;
  }
}

// ---------------- G: C(32768x640) = A(32768x640,bf16) @ Bw^T(640x640 [n][k],bf16)
// R3-proven single-buffer structure: 128x128, 4 waves, gload_lds + vmcnt(0) +
// __syncthreads per K-tile; T1 XCD swizzle; T2 pre-swizzled source + swizzled read.
// MODE 0: out bf16 (B,N,C)  (operand-swapped MFMA)
// MODE 1: out f32  (B,C,N) + bias
template <int MODE>
__global__ __launch_bounds__(256) void k_gemm(const u16* __restrict__ A,
                                              const u16* __restrict__ Bw,
                                              const float* __restrict__ bias,
                                              u16* __restrict__ outb,
                                              float* __restrict__ outf) {
  __shared__ __align__(16) u16 sA[128 * 64];
  __shared__ __align__(16) u16 sB[128 * 64];
  const int bid = blockIdx.x;
  const int logical = (bid & 7) * 160 + (bid >> 3);  // T1 XCD swizzle (1280%8==0)
  const int cb = logical % 5, rb = logical / 5;
  const int r0 = rb * 128, c0 = cb * 128;
  const int t = threadIdx.x;
  const int w = t >> 6, lane = t & 63;
  const int wm = w >> 1, wn = w & 1;
  const int fr = lane & 15, g = lane >> 4;
  const int lr = lane >> 3, ls = lane & 7;
  const int sslot = ls ^ lr;  // pre-swizzled k-slot (row&7 == lr)

  f32x4 acc[4][4];
  f32x4 z4 = {0.f, 0.f, 0.f, 0.f};
#pragma unroll
  for (int i = 0; i < 4; ++i)
#pragma unroll
    for (int j = 0; j < 4; ++j) acc[i][j] = z4;

  for (int ks = 0; ks < 10; ++ks) {
    const int k0 = ks * 64;
#pragma unroll
    for (int p = 0; p < 4; ++p) {
      int q = w * 4 + p;           // chunk: rows q*8 .. q*8+7
      int row = q * 8 + lr;
      gload_lds16(A + (size_t)(r0 + row) * NC + k0 + sslot * 8, sA + q * 512);
      gload_lds16(Bw + (size_t)(c0 + row) * NC + k0 + sslot * 8, sB + q * 512);
    }
    asm volatile("s_waitcnt vmcnt(0)" ::: "memory");
    __syncthreads();
#pragma unroll
    for (int kk = 0; kk < 2; ++kk) {
      bf16x8 af[4], bfr[4];
#pragma unroll
      for (int mt = 0; mt < 4; ++mt) {
        int row = wm * 64 + mt * 16 + fr;
        af[mt] = *(const bf16x8*)((const char*)sA + row * 128 +
                                  ((kk * 64 + g * 16) ^ ((row & 7) << 4)));
      }
#pragma unroll
      for (int nt = 0; nt < 4; ++nt) {
        int row = wn * 64 + nt * 16 + fr;
        bfr[nt] = *(const bf16x8*)((const char*)sB + row * 128 +
                                   ((kk * 64 + g * 16) ^ ((row & 7) << 4)));
      }
#pragma unroll
      for (int mt = 0; mt < 4; ++mt)
#pragma unroll
        for (int nt = 0; nt < 4; ++nt) {
          if (MODE == 0)
            acc[mt][nt] = mfma16(bfr[nt], af[mt], acc[mt][nt]);  // D: row<->c, col<->n
          else
            acc[mt][nt] = mfma16(af[mt], bfr[nt], acc[mt][nt]);  // D: row<->n, col<->c
        }
    }
    __syncthreads();
  }
  const int b = r0 >> 12, n0 = r0 & 4095;
  if (MODE == 0) {
    // D[row=g*4+r <-> c][col=fr <-> n]; write (B,N,C), contiguous along c
#pragma unroll
    for (int mt = 0; mt < 4; ++mt) {
      int n = n0 + wm * 64 + mt * 16 + fr;
#pragma unroll
      for (int nt = 0; nt < 4; ++nt) {
        int cbs = c0 + wn * 64 + nt * 16 + g * 4;
        u16x4 o;
#pragma unroll
        for (int r2 = 0; r2 < 4; ++r2) o[r2] = f2bf(acc[mt][nt][r2]);
        *(u16x4*)(outb + ((size_t)(b * NN + n)) * NC + cbs) = o;
      }
    }
  } else {
    // D[row=g*4+r <-> n][col=fr <-> c]; write (B,C,N) f32 + bias
#pragma unroll
    for (int mt = 0; mt < 4; ++mt) {
      int n = n0 + wm * 64 + mt * 16 + g * 4;
#pragma unroll
      for (int nt = 0; nt < 4; ++nt) {
        int c = c0 + wn * 64 + nt * 16 + fr;
        float bv = bias[c];
        f32x4 o;
#pragma unroll
        for (int r2 = 0; r2 < 4; ++r2) o[r2] = acc[mt][nt][r2] + bv;
        *(f32x4*)(outf + (((size_t)(b * NC + c)) << 12) + n) = o;
      }
    }
  }
}

// ---------------- A1: fused attention, one (b,h,64 q-rows) per block
// qbf (B,N,C) bf16 (scale folded); kbf (B,H,80,80); vtbf (B,H,80,96); obf (B,N,C)
// Swapped QK^T: S[l][n] so softmax reduce = per-lane + 2 shfl_xor.
// Only LDS use: per-wave 16x104 P bounce (vectorized, conflict-free).
__global__ __launch_bounds__(256) void k_attn(const u16* __restrict__ qbf,
                                              const u16* __restrict__ kbf,
                                              const u16* __restrict__ vtbf,
                                              u16* __restrict__ obf) {
  __shared__ __align__(16) u16 sP[4][16][104];
  const int bid = blockIdx.x;
  const int n0 = (bid & 63) * 64, h = (bid >> 6) & 7, b = bid >> 9;
  const int t = threadIdx.x, w = t >> 6, lane = t & 63;
  const int fr = lane & 15, g = lane >> 4;

  // Q fragments: arg2 role, fr = q-row, 8 d-elems per (kk,g)
  const size_t qrow = ((size_t)(b * NN + n0 + w * 16 + fr)) * NC + h * NDH;
  bf16x8 qf[3];
#pragma unroll
  for (int kk = 0; kk < 3; ++kk) {
    int d0 = kk * 32 + g * 8;
    bf16x8 v = {};
    if (d0 < NDH) v = *(const bf16x8*)(qbf + qrow + d0);
    qf[kk] = v;
  }
  // QK^T swapped: S tile nt: row(g*4+r)=l-16nt, col(fr)=n-local
  const size_t kbase = ((size_t)(b * NH + h)) * (80 * 80);
  f32x4 s[5];
  f32x4 z4 = {0.f, 0.f, 0.f, 0.f};
#pragma unroll
  for (int nt = 0; nt < 5; ++nt) s[nt] = z4;
#pragma unroll
  for (int nt = 0; nt < 5; ++nt) {
    const u16* krow = kbf + kbase + (size_t)(nt * 16 + fr) * 80;
#pragma unroll
    for (int kk = 0; kk < 3; ++kk) {
      int d0 = kk * 32 + g * 8;
      bf16x8 kv = {};
      if (d0 < NDH) kv = *(const bf16x8*)(krow + d0);
      s[nt] = mfma16(kv, qf[kk], s[nt]);
    }
  }
  // V^T fragments issued early (independent of softmax)
  const size_t vbase = ((size_t)(b * NH + h)) * (80 * 96);
  bf16x8 vf[5][3];
#pragma unroll
  for (int nt = 0; nt < 5; ++nt)
#pragma unroll
    for (int kk = 0; kk < 3; ++kk)
      vf[nt][kk] = *(const bf16x8*)(vtbf + vbase + (size_t)(nt * 16 + fr) * 96 +
                                    kk * 32 + g * 8);
  // softmax over l (per-lane 20 vals + 2 shfls); no max-sub (|s| small, f32-safe)
  float sum = 0.f;
#pragma unroll
  for (int nt = 0; nt < 5; ++nt)
#pragma unroll
    for (int r = 0; r < 4; ++r) {
      int l = nt * 16 + g * 4 + r;
      float ev = (l < NL) ? __expf(s[nt][r]) : 0.f;
      s[nt][r] = ev;
      sum += ev;
    }
  sum += __shfl_xor(sum, 16);
  sum += __shfl_xor(sum, 32);
  float inv = 1.0f / sum;
  // P -> per-wave LDS tile [n_local=fr][l], normalized bf16
#pragma unroll
  for (int nt = 0; nt < 5; ++nt) {
    u16x4 o;
#pragma unroll
    for (int r = 0; r < 4; ++r) o[r] = f2bf(s[nt][r] * inv);
    *(u16x4*)&sP[w][fr][nt * 16 + g * 4] = o;
  }
  __syncthreads();
  // PV: O[n][d] = P[n][l] V^T[d][l]
  bf16x8 ap[3];
#pragma unroll
  for (int kk = 0; kk < 3; ++kk) {
    int l0 = kk * 32 + g * 8;
    bf16x8 v = {};
    if (l0 < 80) v = *(const bf16x8*)&sP[w][fr][l0];
    ap[kk] = v;
  }
  f32x4 o[5];
#pragma unroll
  for (int nt = 0; nt < 5; ++nt) o[nt] = z4;
#pragma unroll
  for (int nt = 0; nt < 5; ++nt)
#pragma unroll
    for (int kk = 0; kk < 3; ++kk)
      o[nt] = mfma16(ap[kk], vf[nt][kk], o[nt]);
  // store: O[n = n0+w*16+g*4+r][d = nt*16+fr] -> obf (B,N,C)
#pragma unroll
  for (int nt = 0; nt < 5; ++nt)
#pragma unroll
    for (int r = 0; r < 4; ++r)
      obf[((size_t)(b * NN + n0 + w * 16 + g * 4 + r)) * NC + h * NDH + nt * 16 + fr] =
          f2bf(o[nt][r]);
}

extern "C" void kernel_launch(void* const* d_in, const int* in_sizes, int n_in,
                              void* d_out, int out_size, void* d_ws, size_t ws_size,
                              hipStream_t stream) {
  const float* hs  = (const float*)d_in[0];
  const float* ehs = (const float*)d_in[1];
  const float* Wq  = (const float*)d_in[2];
  const float* Wk  = (const float*)d_in[3];
  const float* Wv  = (const float*)d_in[4];
  const float* Wo  = (const float*)d_in[5];
  const float* bo  = (const float*)d_in[6];
  float* out = (float*)d_out;
  float* sal = out + (size_t)NB * NC * NN;

  u16* ws16 = (u16*)d_ws;
  const size_t xn = (size_t)NB * NN * NC;  // 20,971,520
  u16* xbf = ws16;            // also obf (xbf dead after gemm<0>)
  u16* qbf = ws16 + xn;
  u16* wqt = qbf + xn;
  u16* wot = wqt + (size_t)NC * NC;
  u16* kbf = wot + (size_t)NC * NC;                 // B*H*80*80
  u16* vtbf = kbf + (size_t)NB * NH * 80 * 80;      // B*H*80*96
  u16* obf = xbf;

  k_prep<<<7008, 256, 0, stream>>>(hs, ehs, Wq, Wk, Wv, Wo,
                                   xbf, wqt, wot, kbf, vtbf, sal);
  k_gemm<0><<<1280, 256, 0, stream>>>(xbf, wqt, nullptr, qbf, nullptr);
  k_attn<<<NB * NH * 64, 256, 0, stream>>>(qbf, kbf, vtbf, obf);
  k_gemm<1><<<1280, 256, 0, stream>>>(obf, wot, bo, nullptr, out);
}